// Round 6
// baseline (181.911 us; speedup 1.0000x reference)
//
#include <hip/hip_runtime.h>
#include <hip/hip_bf16.h>
#include <stdint.h>

typedef __bf16 bf16;
typedef __bf16 bf16x2 __attribute__((ext_vector_type(2)));
typedef __bf16 bf16x4 __attribute__((ext_vector_type(4)));
typedef __bf16 bf16x8 __attribute__((ext_vector_type(8)));
typedef float f32x4 __attribute__((ext_vector_type(4)));
typedef float f32x16 __attribute__((ext_vector_type(16)));
typedef unsigned int u32;
typedef u32 u32x4 __attribute__((ext_vector_type(4)));
typedef unsigned long long u64;

#define MFMA16(a, b, c) __builtin_amdgcn_mfma_f32_16x16x32_bf16((a), (b), (c), 0, 0, 0)
#define MFMA32(a, b, c) __builtin_amdgcn_mfma_f32_32x32x16_bf16((a), (b), (c), 0, 0, 0)

constexpr int Bc = 2, Sc = 2048, Dc = 1024, Hc = 16, DKc = 64;
constexpr int Mc = Bc * Sc;
constexpr int MW = Sc / 64;
// 1/sqrt(dk) * log2(e): scores produced directly in log2 domain
#define QSCALE 0.1803368801111731f

__device__ __forceinline__ u32 pk2(float a, float b) {
  bf16x2 t; t[0] = (bf16)a; t[1] = (bf16)b;
  return __builtin_bit_cast(u32, t);
}

__device__ __forceinline__ void gl_lds16(const void* g, void* l) {
  __builtin_amdgcn_global_load_lds((const __attribute__((address_space(1))) void*)g,
                                   (__attribute__((address_space(3))) void*)l, 16, 0, 0);
}

// ---------------- weights fp32 -> bf16 (Wq also scaled by QSCALE) ----------------
__global__ __launch_bounds__(256) void convw_kernel(
    const float* __restrict__ wq, const float* __restrict__ wk,
    const float* __restrict__ wv, const float* __restrict__ wo,
    bf16* __restrict__ dq, bf16* __restrict__ dk2, bf16* __restrict__ dv, bf16* __restrict__ dwo) {
  const int a = blockIdx.y;
  const float* src = a == 0 ? wq : a == 1 ? wk : a == 2 ? wv : wo;
  bf16* dst = a == 0 ? dq : a == 1 ? dk2 : a == 2 ? dv : dwo;
  const float sc = a == 0 ? QSCALE : 1.0f;
  const size_t i = ((size_t)blockIdx.x * 256 + threadIdx.x) * 8;
  f32x4 x0 = *(const f32x4*)&src[i];
  f32x4 x1 = *(const f32x4*)&src[i + 4];
  bf16x8 o;
#pragma unroll
  for (int j = 0; j < 4; ++j) { o[j] = (bf16)(x0[j] * sc); o[4 + j] = (bf16)(x1[j] * sc); }
  *(bf16x8*)&dst[i] = o;
}

// ---------------- mask (int32 0/1) -> 64-bit bitmask ----------------
__global__ __launch_bounds__(256) void packmask_kernel(const int* __restrict__ mask,
                                                       u64* __restrict__ mb, int nwords) {
  const int lane = threadIdx.x & 63;
  const int wid = (blockIdx.x * blockDim.x + threadIdx.x) >> 6;
  const int nw = (gridDim.x * blockDim.x) >> 6;
  for (int i = wid; i < nwords; i += nw) {
    int v = mask[(size_t)i * 64 + lane];
    u64 bits = __ballot(v != 0);
    if (lane == 0) mb[i] = bits;
  }
}

// ---------------- fused QKV GEMM (unchanged) ----------------
__global__ __launch_bounds__(256, 2) void gemm_qkv_kernel(
    const float* __restrict__ q, const float* __restrict__ k, const float* __restrict__ v,
    const bf16* __restrict__ wq, const bf16* __restrict__ wk, const bf16* __restrict__ wv,
    const float* __restrict__ bq, const float* __restrict__ bk, const float* __restrict__ bv,
    bf16* __restrict__ qh, bf16* __restrict__ kh, bf16* __restrict__ vt) {
  __shared__ float As[128 * 64];
  __shared__ bf16 Bs[128 * 64];
  const int d = blockIdx.x;
  const int xcd = d & 7, idx = d >> 3;
  const int proj = idx >> 5, w = idx & 31;
  const int n0 = (w & 7) * 128;
  const int m0 = (xcd * 4 + (w >> 3)) * 128;
  const float* Af = proj == 0 ? q : proj == 1 ? k : v;
  const bf16* Bw = proj == 0 ? wq : proj == 1 ? wk : wv;
  const float* bias = proj == 0 ? bq : proj == 1 ? bk : bv;

  const int t = threadIdx.x, lane = t & 63, wv4 = t >> 6;
  const int c = lane & 15, g = lane >> 4;
  const int wr = wv4 >> 1, wc = wv4 & 1;

  f32x4 acc[4][4];
#pragma unroll
  for (int i = 0; i < 4; ++i)
#pragma unroll
    for (int j = 0; j < 4; ++j) acc[i][j] = (f32x4){0.f, 0.f, 0.f, 0.f};

  const int arow_l = lane >> 4;
  const int aslot_l = lane & 15;
  const int brow_l = lane >> 3;
  const int bslot_l = (lane & 7) ^ brow_l;

  for (int k0 = 0; k0 < Dc; k0 += 64) {
#pragma unroll
    for (int u = 0; u < 8; ++u) {
      const int ch = wv4 * 8 + u;
      const int row = ch * 4 + arow_l;
      const int slot = aslot_l ^ (row & 7);
      gl_lds16(&Af[(size_t)(m0 + row) * Dc + k0 + slot * 4], &As[ch * 256]);
    }
#pragma unroll
    for (int u = 0; u < 4; ++u) {
      const int ch = wv4 * 4 + u;
      const int row = ch * 8 + brow_l;
      gl_lds16(&Bw[(size_t)(n0 + row) * Dc + k0 + bslot_l * 8], &Bs[ch * 512]);
    }
    __syncthreads();
#pragma unroll
    for (int ks = 0; ks < 2; ++ks) {
      bf16x8 af[4], bfr[4];
#pragma unroll
      for (int mt = 0; mt < 4; ++mt) {
        const int row = wr * 64 + mt * 16 + c;
        const int s0 = (8 * ks + 2 * g) ^ (c & 7);
        const int s1 = (8 * ks + 2 * g + 1) ^ (c & 7);
        f32x4 lo = *(const f32x4*)&As[row * 64 + s0 * 4];
        f32x4 hi2 = *(const f32x4*)&As[row * 64 + s1 * 4];
#pragma unroll
        for (int j = 0; j < 4; ++j) { af[mt][j] = (bf16)lo[j]; af[mt][4 + j] = (bf16)hi2[j]; }
      }
#pragma unroll
      for (int nt = 0; nt < 4; ++nt) {
        const int row = wc * 64 + nt * 16 + c;
        const int sl = (4 * ks + g) ^ (c & 7);
        bfr[nt] = *(const bf16x8*)&Bs[row * 64 + sl * 8];
      }
#pragma unroll
      for (int mt = 0; mt < 4; ++mt)
#pragma unroll
        for (int nt = 0; nt < 4; ++nt) acc[mt][nt] = MFMA16(af[mt], bfr[nt], acc[mt][nt]);
    }
    __syncthreads();
  }

  const float bsc = proj == 0 ? QSCALE : 1.0f;
  const int colb = n0 + wc * 64 + c;
  const int mrowb = m0 + wr * 64 + 4 * g;
#pragma unroll
  for (int mt = 0; mt < 4; ++mt) {
#pragma unroll
    for (int nt = 0; nt < 4; ++nt) {
      const int col = colb + nt * 16;
      const int mrow = mrowb + mt * 16;
      const float bb = bias[col] * bsc;
      f32x4 a = acc[mt][nt];
      if (proj == 0) {
#pragma unroll
        for (int r = 0; r < 4; ++r) qh[(size_t)(mrow + r) * Dc + col] = (bf16)(a[r] + bb);
      } else if (proj == 1) {
        const int hh = col >> 6, dd = col & 63;
#pragma unroll
        for (int r = 0; r < 4; ++r) {
          const int mr = mrow + r;
          kh[((size_t)((mr >> 11) * Hc + hh) * Sc + (mr & (Sc - 1))) * DKc + dd] = (bf16)(a[r] + bb);
        }
      } else {
        const int batch = mrow >> 11, s = mrow & (Sc - 1);
        const int hh = col >> 6, dd = col & 63;
        bf16x4 pkv;
#pragma unroll
        for (int r = 0; r < 4; ++r) pkv[r] = (bf16)(a[r] + bb);
        *(bf16x4*)&vt[((size_t)((batch * Hc + hh) * DKc + dd)) * Sc + s] = pkv;
      }
    }
  }
}

// ---------------- output GEMM (unchanged) ----------------
__global__ __launch_bounds__(256, 2) void gemm_o_kernel(const bf16* __restrict__ ctxp,
                                                        const bf16* __restrict__ wo,
                                                        const float* __restrict__ bo,
                                                        float* __restrict__ outp) {
  __shared__ bf16 As[128 * 64];
  __shared__ bf16 Bs[64 * 64];
  const int d = blockIdx.x;
  const int xcd = d & 7, idx = d >> 3;
  const int n0 = (idx & 15) * 64;
  const int m0 = (xcd * 4 + (idx >> 4)) * 128;

  const int t = threadIdx.x, lane = t & 63, wv4 = t >> 6;
  const int c = lane & 15, g = lane >> 4;
  const int brow_l = lane >> 3;
  const int bslot_l = (lane & 7) ^ brow_l;

  f32x4 acc[2][4];
#pragma unroll
  for (int i = 0; i < 2; ++i)
#pragma unroll
    for (int j = 0; j < 4; ++j) acc[i][j] = (f32x4){0.f, 0.f, 0.f, 0.f};

  for (int k0 = 0; k0 < Dc; k0 += 64) {
#pragma unroll
    for (int u = 0; u < 4; ++u) {
      const int ch = wv4 * 4 + u;
      const int row = ch * 8 + brow_l;
      gl_lds16(&ctxp[(size_t)(m0 + row) * Dc + k0 + bslot_l * 8], &As[ch * 512]);
    }
    {
      const int ch = wv4;
      const int row = ch * 8 + brow_l;
      gl_lds16(&wo[(size_t)(n0 + row) * Dc + k0 + bslot_l * 8], &Bs[ch * 512]);
      const int ch2 = 4 + wv4;
      const int row2 = ch2 * 8 + brow_l;
      gl_lds16(&wo[(size_t)(n0 + row2) * Dc + k0 + bslot_l * 8], &Bs[ch2 * 512]);
    }
    __syncthreads();
#pragma unroll
    for (int ks = 0; ks < 2; ++ks) {
      bf16x8 af[2], bfr[4];
#pragma unroll
      for (int mt = 0; mt < 2; ++mt) {
        const int row = wv4 * 32 + mt * 16 + c;
        const int sl = (4 * ks + g) ^ (c & 7);
        af[mt] = *(const bf16x8*)&As[row * 64 + sl * 8];
      }
#pragma unroll
      for (int nt = 0; nt < 4; ++nt) {
        const int row = nt * 16 + c;
        const int sl = (4 * ks + g) ^ (c & 7);
        bfr[nt] = *(const bf16x8*)&Bs[row * 64 + sl * 8];
      }
#pragma unroll
      for (int mt = 0; mt < 2; ++mt)
#pragma unroll
        for (int nt = 0; nt < 4; ++nt) acc[mt][nt] = MFMA16(af[mt], bfr[nt], acc[mt][nt]);
    }
    __syncthreads();
  }

  const int colb = n0 + c;
  const int mrowb = m0 + wv4 * 32 + 4 * g;
#pragma unroll
  for (int mt = 0; mt < 2; ++mt)
#pragma unroll
    for (int nt = 0; nt < 4; ++nt) {
      const int col = colb + nt * 16;
      const int mrow = mrowb + mt * 16;
      const float bb = bo[col];
      f32x4 a = acc[mt][nt];
#pragma unroll
      for (int r = 0; r < 4; ++r) outp[(size_t)(mrow + r) * Dc + col] = a[r] + bb;
    }
}

// ---------------- flash attention: one-barrier async pipeline, fixed-base softmax ----------------
// Per iter: [issue stage(next buf); load mask(next); compute(cur); vmcnt(0) (ops issued a full
// compute ago -> no stall) ; s_barrier (all waves' stages visible)]. No mid-iter memory waits.
template <int SPLITS>
__global__ __launch_bounds__(256, 4) void attn_kernel(const bf16* __restrict__ qh,
                                                      const bf16* __restrict__ kh,
                                                      const bf16* __restrict__ vt,
                                                      const u64* __restrict__ mb,
                                                      bf16* __restrict__ ctx,
                                                      float* __restrict__ opart,
                                                      float2* __restrict__ ml) {
  __shared__ bf16 Ks[2][64 * 64];   // [buf][row 64][col 64], 16B slots XOR-swizzled by row&7
  __shared__ bf16 Vs[2][64 * 64];
  const int d = blockIdx.x;
  const int xcd = d & 7, idx = d >> 3;
  int bh, qt, half;
  if constexpr (SPLITS == 2) {
    bh = xcd * 4 + (idx >> 5);
    const int sub = idx & 31;
    qt = sub >> 1; half = sub & 1;
  } else {
    bh = xcd * 4 + (idx >> 4);
    qt = idx & 15; half = 0;
  }
  const int b = bh >> 4, h = bh & 15;
  const int lane = threadIdx.x & 63, wv4 = threadIdx.x >> 6;
  const int ql = lane & 31, hi = lane >> 5;
  const int qrow = qt * 128 + wv4 * 32 + ql;

  const bf16* Qp = qh + (size_t)(b * Sc + qrow) * Dc + h * DKc;
  const bf16* Kp = kh + (size_t)(b * Hc + h) * Sc * DKc;
  const bf16* Vp = vt + (size_t)(b * Hc + h) * DKc * Sc;
  const u64* mbp = mb + (size_t)(b * Sc + qrow) * MW;

  const int k0 = half * (Sc / SPLITS);
  constexpr int NIT = (Sc / SPLITS) / 64;

  const int srow = lane >> 3, sslot = lane & 7;
  auto stage = [&](int buf, int kt) {
#pragma unroll
    for (int u = 0; u < 2; ++u) {
      const int rb = wv4 * 16 + u * 8;
      const int r = rb + srow;
      gl_lds16(&Kp[(size_t)(kt + r) * DKc + (size_t)((sslot ^ (r & 7)) * 8)], &Ks[buf][rb * 64]);
    }
#pragma unroll
    for (int u = 0; u < 2; ++u) {
      const int rb = wv4 * 16 + u * 8;
      const int r = rb + srow;
      gl_lds16(&Vp[(size_t)r * Sc + kt + (sslot ^ (r & 7)) * 8], &Vs[buf][rb * 64]);
    }
  };

  bf16x8 qf[4];
#pragma unroll
  for (int ka = 0; ka < 4; ++ka) qf[ka] = *(const bf16x8*)&Qp[16 * ka + 8 * hi];

  bf16x8 ones8;
#pragma unroll
  for (int j = 0; j < 8; ++j) ones8[j] = (bf16)1.0f;

  f32x16 oacc[2], lacc;
#pragma unroll
  for (int i = 0; i < 2; ++i)
#pragma unroll
    for (int r = 0; r < 16; ++r) oacc[i][r] = 0.f;
#pragma unroll
  for (int r = 0; r < 16; ++r) lacc[r] = 0.f;

  // prologue: stage tile 0 + its mask, drain own ops, then block-wide visibility barrier
  stage(0, k0);
  u64 w = mbp[k0 >> 6];
  asm volatile("s_waitcnt vmcnt(0)" ::: "memory");
  __builtin_amdgcn_s_barrier();

  for (int it = 0; it < NIT; ++it) {
    const int kt = k0 + it * 64;
    const int buf = it & 1;
    const int ktn = (it + 1 < NIT) ? kt + 64 : kt;  // clamp: harmless restage on last iter
    // issue next-tile staging + next mask load; both retire during compute below
    stage(buf ^ 1, ktn);
    const u64 wnext = mbp[ktn >> 6];

    // ---- QK^T from LDS: st[tt] covers k in [kt+32tt, +32), all 32 q ----
    f32x16 st[2];
#pragma unroll
    for (int tt = 0; tt < 2; ++tt) {
      const int row = 32 * tt + ql;
      const bf16* kbase = &Ks[buf][row * 64];
      f32x16 z;
#pragma unroll
      for (int r = 0; r < 16; ++r) z[r] = 0.f;
      __builtin_amdgcn_s_setprio(1);
#pragma unroll
      for (int ka = 0; ka < 4; ++ka) {
        bf16x8 kf = *(const bf16x8*)&kbase[((2 * ka + hi) ^ (row & 7)) * 8];
        z = MFMA32(kf, qf[ka], z);
      }
      __builtin_amdgcn_s_setprio(0);
      st[tt] = z;
    }

    // ---- fixed-base softmax: p = exp2(s) (scale cancels in o = sum(p*v)/sum(p)) ----
    const u32 wt0 = (u32)(w >> (4 * hi));
    const u32 wt1 = (u32)(w >> (32 + 4 * hi));
#pragma unroll
    for (int tt = 0; tt < 2; ++tt) {
      const u32 wt = tt ? wt1 : wt0;
#pragma unroll
      for (int r = 0; r < 16; ++r) {
        const int bit = (r & 3) + 8 * (r >> 2);
        const float p = exp2f((float)st[tt][r]);
        st[tt][r] = ((wt >> bit) & 1u) ? p : 0.f;
      }
    }

    // ---- pack P -> PV B-frags ----
    u32x4 pb[4];
#pragma unroll
    for (int tt = 0; tt < 2; ++tt) {
      u32 G[4][2];
#pragma unroll
      for (int i = 0; i < 4; ++i) {
        G[i][0] = pk2((float)st[tt][4 * i + 0], (float)st[tt][4 * i + 1]);
        G[i][1] = pk2((float)st[tt][4 * i + 2], (float)st[tt][4 * i + 3]);
      }
#pragma unroll
      for (int e = 0; e < 2; ++e) {
        const u32 xlo = hi ? G[2 * e][0] : G[2 * e + 1][0];
        const u32 xhi = hi ? G[2 * e][1] : G[2 * e + 1][1];
        const u32 rlo = __shfl_xor(xlo, 32);
        const u32 rhi = __shfl_xor(xhi, 32);
        const int ks = 2 * tt + e;
        if (hi) { pb[ks][0] = rlo; pb[ks][1] = rhi; pb[ks][2] = G[2 * e + 1][0]; pb[ks][3] = G[2 * e + 1][1]; }
        else    { pb[ks][0] = G[2 * e][0]; pb[ks][1] = G[2 * e][1]; pb[ks][2] = rlo; pb[ks][3] = rhi; }
      }
    }

    // ---- l += P^T-colsum via ones-MFMA; PV from LDS ----
    __builtin_amdgcn_s_setprio(1);
#pragma unroll
    for (int ks = 0; ks < 4; ++ks)
      lacc = MFMA32(ones8, __builtin_bit_cast(bf16x8, pb[ks]), lacc);
#pragma unroll
    for (int dt = 0; dt < 2; ++dt) {
      const int row = 32 * dt + ql;
      const bf16* vbase = &Vs[buf][row * 64];
#pragma unroll
      for (int ks = 0; ks < 4; ++ks) {
        bf16x8 vf = *(const bf16x8*)&vbase[((2 * ks + hi) ^ (row & 7)) * 8];
        oacc[dt] = MFMA32(vf, __builtin_bit_cast(bf16x8, pb[ks]), oacc[dt]);
      }
    }
    __builtin_amdgcn_s_setprio(0);

    // ops below were issued before compute (~2000 cyc ago) -> retire instantly
    asm volatile("s_waitcnt vmcnt(0)" ::: "memory");
    __builtin_amdgcn_s_barrier();  // all waves' next-buf stages now visible
    w = wnext;
  }

  const float lsum = lacc[0];  // every reg row holds the same column-sum
  if constexpr (SPLITS == 2) {
    float* opr = opart + ((size_t)(half * 32 + bh) * Sc + qrow) * 64;
#pragma unroll
    for (int dt = 0; dt < 2; ++dt)
#pragma unroll
      for (int i = 0; i < 4; ++i) {
        f32x4 o4;
#pragma unroll
        for (int rr = 0; rr < 4; ++rr) o4[rr] = oacc[dt][4 * i + rr];
        *(f32x4*)&opr[32 * dt + 8 * i + 4 * hi] = o4;
      }
    if (hi == 0) {
      float2 v2; v2.x = 0.f; v2.y = lsum;  // fixed base: m = 0 for both halves
      ml[(size_t)(half * 32 + bh) * Sc + qrow] = v2;
    }
  } else {
    const float rinv = 1.f / fmaxf(lsum, 1e-35f);
    bf16* cp = ctx + (size_t)(b * Sc + qrow) * Dc + h * DKc;
#pragma unroll
    for (int dt = 0; dt < 2; ++dt)
#pragma unroll
      for (int i = 0; i < 4; ++i) {
        bf16x4 o4;
#pragma unroll
        for (int rr = 0; rr < 4; ++rr) o4[rr] = (bf16)(oacc[dt][4 * i + rr] * rinv);
        *(bf16x4*)&cp[32 * dt + 8 * i + 4 * hi] = o4;
      }
  }
}

// ---------------- combine the two KV-splits: exact f32 flash merge ----------------
__global__ __launch_bounds__(256) void combine_kernel(const float* __restrict__ op,
                                                      const float2* __restrict__ ml,
                                                      bf16* __restrict__ ctx) {
  const int wv = threadIdx.x >> 6, lane = threadIdx.x & 63;
  const size_t row = (size_t)blockIdx.x * 4 + wv;      // bh*2048 + q, 0..65535
  const int bh = (int)(row >> 11), q = (int)(row & 2047);
  const int b = bh >> 4, h = bh & 15;
  const float2 ml0 = ml[row], ml1 = ml[65536 + row];
  const float o0 = op[row * 64 + lane];
  const float o1 = op[(size_t)65536 * 64 + row * 64 + lane];
  const float m = fmaxf(ml0.x, ml1.x);
  const float a0 = exp2f(ml0.x - m), a1 = exp2f(ml1.x - m);
  const float l = fmaxf(a0 * ml0.y + a1 * ml1.y, 1e-35f);
  const float o = (a0 * o0 + a1 * o1) / l;
  ctx[((size_t)(b * Sc + q)) * Dc + h * DKc + lane] = (bf16)o;
}

extern "C" void kernel_launch(void* const* d_in, const int* in_sizes, int n_in,
                              void* d_out, int out_size, void* d_ws, size_t ws_size,
                              hipStream_t stream) {
  (void)in_sizes; (void)n_in; (void)out_size;
  const float* q  = (const float*)d_in[0];
  const float* k  = (const float*)d_in[1];
  const float* v  = (const float*)d_in[2];
  const float* Wq = (const float*)d_in[3];
  const float* bq = (const float*)d_in[4];
  const float* Wk = (const float*)d_in[5];
  const float* bk = (const float*)d_in[6];
  const float* Wv = (const float*)d_in[7];
  const float* bv = (const float*)d_in[8];
  const float* Wo = (const float*)d_in[9];
  const float* bo = (const float*)d_in[10];
  const int* mask = (const int*)d_in[11];

  char* ws = (char*)d_ws;
  size_t off = 0;
  auto take = [&](size_t bytes) -> void* {
    void* p = ws + off;
    off += (bytes + 255) & ~(size_t)255;
    return p;
  };
  bf16* qh  = (bf16*)take((size_t)Mc * Dc * 2);
  bf16* kh  = (bf16*)take((size_t)Mc * Dc * 2);
  bf16* vt  = (bf16*)take((size_t)Mc * Dc * 2);
  bf16* ctx = (bf16*)take((size_t)Mc * Dc * 2);
  u64* mbits = (u64*)take((size_t)Bc * Sc * MW * 8);
  bf16* wqb = (bf16*)take((size_t)Dc * Dc * 2);
  bf16* wkb = (bf16*)take((size_t)Dc * Dc * 2);
  bf16* wvb = (bf16*)take((size_t)Dc * Dc * 2);
  bf16* wob = (bf16*)take((size_t)Dc * Dc * 2);
  float* opart = (float*)take((size_t)2 * 32 * Sc * 64 * 4);   // [split][bh][q][64] f32
  float2* mlb = (float2*)take((size_t)2 * 32 * Sc * 8);        // [split][bh][q] (m,l)
  const bool split2 = off <= ws_size;

  convw_kernel<<<dim3(512, 4), 256, 0, stream>>>(Wq, Wk, Wv, Wo, wqb, wkb, wvb, wob);
  packmask_kernel<<<512, 256, 0, stream>>>(mask, mbits, Bc * Sc * Sc / 64);
  gemm_qkv_kernel<<<768, 256, 0, stream>>>(q, k, v, wqb, wkb, wvb, bq, bk, bv, qh, kh, vt);
  if (split2) {
    attn_kernel<2><<<1024, 256, 0, stream>>>(qh, kh, vt, mbits, ctx, opart, mlb);
    combine_kernel<<<16384, 256, 0, stream>>>(opart, mlb, ctx);
  } else {
    attn_kernel<1><<<512, 256, 0, stream>>>(qh, kh, vt, mbits, ctx, opart, mlb);
  }
  gemm_o_kernel<<<512, 256, 0, stream>>>(ctx, wob, bo, (float*)d_out);
}

// Round 7
// 177.626 us; speedup vs baseline: 1.0241x; 1.0241x over previous
//
#include <hip/hip_runtime.h>
#include <hip/hip_bf16.h>
#include <stdint.h>

typedef __bf16 bf16;
typedef __bf16 bf16x2 __attribute__((ext_vector_type(2)));
typedef __bf16 bf16x4 __attribute__((ext_vector_type(4)));
typedef __bf16 bf16x8 __attribute__((ext_vector_type(8)));
typedef float f32x4 __attribute__((ext_vector_type(4)));
typedef float f32x16 __attribute__((ext_vector_type(16)));
typedef unsigned int u32;
typedef u32 u32x4 __attribute__((ext_vector_type(4)));
typedef unsigned long long u64;

#define MFMA16(a, b, c) __builtin_amdgcn_mfma_f32_16x16x32_bf16((a), (b), (c), 0, 0, 0)
#define MFMA32(a, b, c) __builtin_amdgcn_mfma_f32_32x32x16_bf16((a), (b), (c), 0, 0, 0)

constexpr int Bc = 2, Sc = 2048, Dc = 1024, Hc = 16, DKc = 64;
constexpr int Mc = Bc * Sc;
constexpr int MW = Sc / 64;
// 1/sqrt(dk) * log2(e): scores produced directly in log2 domain
#define QSCALE 0.1803368801111731f

__device__ __forceinline__ u32 pk2(float a, float b) {
  bf16x2 t; t[0] = (bf16)a; t[1] = (bf16)b;
  return __builtin_bit_cast(u32, t);
}

__device__ __forceinline__ void gl_lds16(const void* g, void* l) {
  __builtin_amdgcn_global_load_lds((const __attribute__((address_space(1))) void*)g,
                                   (__attribute__((address_space(3))) void*)l, 16, 0, 0);
}

// ---------------- weights fp32 -> bf16 (Wq also scaled by QSCALE) ----------------
__global__ __launch_bounds__(256) void convw_kernel(
    const float* __restrict__ wq, const float* __restrict__ wk,
    const float* __restrict__ wv, const float* __restrict__ wo,
    bf16* __restrict__ dq, bf16* __restrict__ dk2, bf16* __restrict__ dv, bf16* __restrict__ dwo) {
  const int a = blockIdx.y;
  const float* src = a == 0 ? wq : a == 1 ? wk : a == 2 ? wv : wo;
  bf16* dst = a == 0 ? dq : a == 1 ? dk2 : a == 2 ? dv : dwo;
  const float sc = a == 0 ? QSCALE : 1.0f;
  const size_t i = ((size_t)blockIdx.x * 256 + threadIdx.x) * 8;
  f32x4 x0 = *(const f32x4*)&src[i];
  f32x4 x1 = *(const f32x4*)&src[i + 4];
  bf16x8 o;
#pragma unroll
  for (int j = 0; j < 4; ++j) { o[j] = (bf16)(x0[j] * sc); o[4 + j] = (bf16)(x1[j] * sc); }
  *(bf16x8*)&dst[i] = o;
}

// ---------------- mask (int32 0/1) -> transposed bitmask mbT[b][kw][q] ----------------
__global__ __launch_bounds__(256) void packmask_kernel(const int* __restrict__ mask,
                                                       u64* __restrict__ mbT, int nwords) {
  const int lane = threadIdx.x & 63;
  const int wid = (blockIdx.x * blockDim.x + threadIdx.x) >> 6;
  const int nw = (gridDim.x * blockDim.x) >> 6;
  for (int i = wid; i < nwords; i += nw) {
    int v = mask[(size_t)i * 64 + lane];
    u64 bits = __ballot(v != 0);
    if (lane == 0) {
      const int kw = i & (MW - 1), bq = i >> 5;
      const int b = bq >> 11, q = bq & (Sc - 1);
      mbT[((size_t)(b * MW + kw)) * Sc + q] = bits;
    }
  }
}

// ---------------- fused QKV GEMM (unchanged) ----------------
__global__ __launch_bounds__(256, 2) void gemm_qkv_kernel(
    const float* __restrict__ q, const float* __restrict__ k, const float* __restrict__ v,
    const bf16* __restrict__ wq, const bf16* __restrict__ wk, const bf16* __restrict__ wv,
    const float* __restrict__ bq, const float* __restrict__ bk, const float* __restrict__ bv,
    bf16* __restrict__ qh, bf16* __restrict__ kh, bf16* __restrict__ vt) {
  __shared__ float As[128 * 64];
  __shared__ bf16 Bs[128 * 64];
  const int d = blockIdx.x;
  const int xcd = d & 7, idx = d >> 3;
  const int proj = idx >> 5, w = idx & 31;
  const int n0 = (w & 7) * 128;
  const int m0 = (xcd * 4 + (w >> 3)) * 128;
  const float* Af = proj == 0 ? q : proj == 1 ? k : v;
  const bf16* Bw = proj == 0 ? wq : proj == 1 ? wk : wv;
  const float* bias = proj == 0 ? bq : proj == 1 ? bk : bv;

  const int t = threadIdx.x, lane = t & 63, wv4 = t >> 6;
  const int c = lane & 15, g = lane >> 4;
  const int wr = wv4 >> 1, wc = wv4 & 1;

  f32x4 acc[4][4];
#pragma unroll
  for (int i = 0; i < 4; ++i)
#pragma unroll
    for (int j = 0; j < 4; ++j) acc[i][j] = (f32x4){0.f, 0.f, 0.f, 0.f};

  const int arow_l = lane >> 4;
  const int aslot_l = lane & 15;
  const int brow_l = lane >> 3;
  const int bslot_l = (lane & 7) ^ brow_l;

  for (int k0 = 0; k0 < Dc; k0 += 64) {
#pragma unroll
    for (int u = 0; u < 8; ++u) {
      const int ch = wv4 * 8 + u;
      const int row = ch * 4 + arow_l;
      const int slot = aslot_l ^ (row & 7);
      gl_lds16(&Af[(size_t)(m0 + row) * Dc + k0 + slot * 4], &As[ch * 256]);
    }
#pragma unroll
    for (int u = 0; u < 4; ++u) {
      const int ch = wv4 * 4 + u;
      const int row = ch * 8 + brow_l;
      gl_lds16(&Bw[(size_t)(n0 + row) * Dc + k0 + bslot_l * 8], &Bs[ch * 512]);
    }
    __syncthreads();
#pragma unroll
    for (int ks = 0; ks < 2; ++ks) {
      bf16x8 af[4], bfr[4];
#pragma unroll
      for (int mt = 0; mt < 4; ++mt) {
        const int row = wr * 64 + mt * 16 + c;
        const int s0 = (8 * ks + 2 * g) ^ (c & 7);
        const int s1 = (8 * ks + 2 * g + 1) ^ (c & 7);
        f32x4 lo = *(const f32x4*)&As[row * 64 + s0 * 4];
        f32x4 hi2 = *(const f32x4*)&As[row * 64 + s1 * 4];
#pragma unroll
        for (int j = 0; j < 4; ++j) { af[mt][j] = (bf16)lo[j]; af[mt][4 + j] = (bf16)hi2[j]; }
      }
#pragma unroll
      for (int nt = 0; nt < 4; ++nt) {
        const int row = wc * 64 + nt * 16 + c;
        const int sl = (4 * ks + g) ^ (c & 7);
        bfr[nt] = *(const bf16x8*)&Bs[row * 64 + sl * 8];
      }
#pragma unroll
      for (int mt = 0; mt < 4; ++mt)
#pragma unroll
        for (int nt = 0; nt < 4; ++nt) acc[mt][nt] = MFMA16(af[mt], bfr[nt], acc[mt][nt]);
    }
    __syncthreads();
  }

  const float bsc = proj == 0 ? QSCALE : 1.0f;
  const int colb = n0 + wc * 64 + c;
  const int mrowb = m0 + wr * 64 + 4 * g;
#pragma unroll
  for (int mt = 0; mt < 4; ++mt) {
#pragma unroll
    for (int nt = 0; nt < 4; ++nt) {
      const int col = colb + nt * 16;
      const int mrow = mrowb + mt * 16;
      const float bb = bias[col] * bsc;
      f32x4 a = acc[mt][nt];
      if (proj == 0) {
#pragma unroll
        for (int r = 0; r < 4; ++r) qh[(size_t)(mrow + r) * Dc + col] = (bf16)(a[r] + bb);
      } else if (proj == 1) {
        const int hh = col >> 6, dd = col & 63;
#pragma unroll
        for (int r = 0; r < 4; ++r) {
          const int mr = mrow + r;
          kh[((size_t)((mr >> 11) * Hc + hh) * Sc + (mr & (Sc - 1))) * DKc + dd] = (bf16)(a[r] + bb);
        }
      } else {
        const int batch = mrow >> 11, s = mrow & (Sc - 1);
        const int hh = col >> 6, dd = col & 63;
        bf16x4 pkv;
#pragma unroll
        for (int r = 0; r < 4; ++r) pkv[r] = (bf16)(a[r] + bb);
        *(bf16x4*)&vt[((size_t)((batch * Hc + hh) * DKc + dd)) * Sc + s] = pkv;
      }
    }
  }
}

// ---------------- output GEMM (unchanged) ----------------
__global__ __launch_bounds__(256, 2) void gemm_o_kernel(const bf16* __restrict__ ctxp,
                                                        const bf16* __restrict__ wo,
                                                        const float* __restrict__ bo,
                                                        float* __restrict__ outp) {
  __shared__ bf16 As[128 * 64];
  __shared__ bf16 Bs[64 * 64];
  const int d = blockIdx.x;
  const int xcd = d & 7, idx = d >> 3;
  const int n0 = (idx & 15) * 64;
  const int m0 = (xcd * 4 + (idx >> 4)) * 128;

  const int t = threadIdx.x, lane = t & 63, wv4 = t >> 6;
  const int c = lane & 15, g = lane >> 4;
  const int brow_l = lane >> 3;
  const int bslot_l = (lane & 7) ^ brow_l;

  f32x4 acc[2][4];
#pragma unroll
  for (int i = 0; i < 2; ++i)
#pragma unroll
    for (int j = 0; j < 4; ++j) acc[i][j] = (f32x4){0.f, 0.f, 0.f, 0.f};

  for (int k0 = 0; k0 < Dc; k0 += 64) {
#pragma unroll
    for (int u = 0; u < 4; ++u) {
      const int ch = wv4 * 4 + u;
      const int row = ch * 8 + brow_l;
      gl_lds16(&ctxp[(size_t)(m0 + row) * Dc + k0 + bslot_l * 8], &As[ch * 512]);
    }
    {
      const int ch = wv4;
      const int row = ch * 8 + brow_l;
      gl_lds16(&wo[(size_t)(n0 + row) * Dc + k0 + bslot_l * 8], &Bs[ch * 512]);
      const int ch2 = 4 + wv4;
      const int row2 = ch2 * 8 + brow_l;
      gl_lds16(&wo[(size_t)(n0 + row2) * Dc + k0 + bslot_l * 8], &Bs[ch2 * 512]);
    }
    __syncthreads();
#pragma unroll
    for (int ks = 0; ks < 2; ++ks) {
      bf16x8 af[2], bfr[4];
#pragma unroll
      for (int mt = 0; mt < 2; ++mt) {
        const int row = wv4 * 32 + mt * 16 + c;
        const int sl = (4 * ks + g) ^ (c & 7);
        af[mt] = *(const bf16x8*)&As[row * 64 + sl * 8];
      }
#pragma unroll
      for (int nt = 0; nt < 4; ++nt) {
        const int row = nt * 16 + c;
        const int sl = (4 * ks + g) ^ (c & 7);
        bfr[nt] = *(const bf16x8*)&Bs[row * 64 + sl * 8];
      }
#pragma unroll
      for (int mt = 0; mt < 2; ++mt)
#pragma unroll
        for (int nt = 0; nt < 4; ++nt) acc[mt][nt] = MFMA16(af[mt], bfr[nt], acc[mt][nt]);
    }
    __syncthreads();
  }

  const int colb = n0 + c;
  const int mrowb = m0 + wv4 * 32 + 4 * g;
#pragma unroll
  for (int mt = 0; mt < 2; ++mt)
#pragma unroll
    for (int nt = 0; nt < 4; ++nt) {
      const int col = colb + nt * 16;
      const int mrow = mrowb + mt * 16;
      const float bb = bo[col];
      f32x4 a = acc[mt][nt];
#pragma unroll
      for (int r = 0; r < 4; ++r) outp[(size_t)(mrow + r) * Dc + col] = a[r] + bb;
    }
}

// ---------------- flash attention: KVBLK=128, zero-shuffle PV, coalesced masks ----------------
// k-map freedom: A/B of one MFMA need only agree (true HW map cancels). Choosing
// k = 4*hi + (j<4 ? j : j+4) makes pb the straight in-order pack of st (no lane exchange);
// V A-frags are 2x ds_read_b64 at matching offsets. One barrier + one vmcnt(0) per 128-k tile.
template <int SPLITS>
__global__ __launch_bounds__(256, 2) void attn_kernel(const bf16* __restrict__ qh,
                                                      const bf16* __restrict__ kh,
                                                      const bf16* __restrict__ vt,
                                                      const u64* __restrict__ mbT,
                                                      bf16* __restrict__ ctx,
                                                      float* __restrict__ opart,
                                                      float2* __restrict__ ml) {
  __shared__ bf16 Ks[2][128 * 64];   // [buf][k-row 128][64], 16B slots XOR-swizzled by row&7
  __shared__ bf16 Vs[2][64 * 128];   // [buf][d-row 64][128], 16 slots XOR-swizzled by row&7
  const int d = blockIdx.x;
  const int xcd = d & 7, idx = d >> 3;
  int bh, qt, half;
  if constexpr (SPLITS == 2) {
    bh = xcd * 4 + (idx >> 5);
    const int sub = idx & 31;
    qt = sub >> 1; half = sub & 1;
  } else {
    bh = xcd * 4 + (idx >> 4);
    qt = idx & 15; half = 0;
  }
  const int b = bh >> 4, h = bh & 15;
  const int lane = threadIdx.x & 63, wv4 = threadIdx.x >> 6;
  const int ql = lane & 31, hi = lane >> 5;
  const int qrow = qt * 128 + wv4 * 32 + ql;

  const bf16* Qp = qh + (size_t)(b * Sc + qrow) * Dc + h * DKc;
  const bf16* Kp = kh + (size_t)(b * Hc + h) * Sc * DKc;
  const bf16* Vp = vt + (size_t)(b * Hc + h) * DKc * Sc;
  const u64* mbp = mbT + (size_t)b * MW * Sc;  // [kw][q], q-coalesced

  const int k0 = half * (Sc / SPLITS);
  constexpr int NIT = (Sc / SPLITS) / 128;

  const int srow = lane >> 3, sslot = lane & 7;     // K staging: 8 rows/chunk
  const int vrow = lane >> 4, vslot = lane & 15;    // V staging: 4 rows/chunk
  auto stage = [&](int buf, int kt) {
#pragma unroll
    for (int u = 0; u < 4; ++u) {
      const int ch = wv4 * 4 + u;
      const int r = ch * 8 + srow;
      gl_lds16(&Kp[(size_t)(kt + r) * DKc + (size_t)((sslot ^ (r & 7)) * 8)], &Ks[buf][ch * 512]);
    }
#pragma unroll
    for (int u = 0; u < 4; ++u) {
      const int ch = wv4 * 4 + u;
      const int r = ch * 4 + vrow;
      gl_lds16(&Vp[(size_t)r * Sc + kt + (size_t)((vslot ^ (r & 7)) * 8)], &Vs[buf][ch * 512]);
    }
  };

  bf16x8 qf[4];
#pragma unroll
  for (int ka = 0; ka < 4; ++ka) qf[ka] = *(const bf16x8*)&Qp[16 * ka + 8 * hi];

  bf16x8 ones8;
#pragma unroll
  for (int j = 0; j < 8; ++j) ones8[j] = (bf16)1.0f;

  f32x16 oacc[2], lacc;
#pragma unroll
  for (int i = 0; i < 2; ++i)
#pragma unroll
    for (int r = 0; r < 16; ++r) oacc[i][r] = 0.f;
#pragma unroll
  for (int r = 0; r < 16; ++r) lacc[r] = 0.f;

  // prologue: stage tile 0 + its two mask words (coalesced), drain, barrier
  stage(0, k0);
  u64 w0 = mbp[(size_t)((k0 >> 6) + 0) * Sc + qrow];
  u64 w1 = mbp[(size_t)((k0 >> 6) + 1) * Sc + qrow];
  asm volatile("s_waitcnt vmcnt(0)" ::: "memory");
  __builtin_amdgcn_s_barrier();
  __builtin_amdgcn_sched_barrier(0);

  for (int it = 0; it < NIT; ++it) {
    const int kt = k0 + it * 128;
    const int buf = it & 1;
    const int ktn = (it + 1 < NIT) ? kt + 128 : kt;  // clamp: harmless restage on last iter
    stage(buf ^ 1, ktn);
    const u64 w0n = mbp[(size_t)((ktn >> 6) + 0) * Sc + qrow];
    const u64 w1n = mbp[(size_t)((ktn >> 6) + 1) * Sc + qrow];

#pragma unroll
    for (int hh = 0; hh < 2; ++hh) {
      const u64 w = hh ? w1 : w0;

      // ---- QK^T from LDS: st[tt] covers k in [kt+64hh+32tt, +32), all 32 q ----
      f32x16 st[2];
#pragma unroll
      for (int tt = 0; tt < 2; ++tt) {
        const int row = 64 * hh + 32 * tt + ql;
        const bf16* kbase = &Ks[buf][row * 64];
        f32x16 z;
#pragma unroll
        for (int r = 0; r < 16; ++r) z[r] = 0.f;
        __builtin_amdgcn_s_setprio(1);
#pragma unroll
        for (int ka = 0; ka < 4; ++ka) {
          bf16x8 kf = *(const bf16x8*)&kbase[((2 * ka + hi) ^ (row & 7)) * 8];
          z = MFMA32(kf, qf[ka], z);
        }
        __builtin_amdgcn_s_setprio(0);
        st[tt] = z;
      }

      // ---- fixed-base softmax: p = exp2(s), mask after ----
      const u32 wt0 = (u32)(w >> (4 * hi));
      const u32 wt1 = (u32)(w >> (32 + 4 * hi));
#pragma unroll
      for (int tt = 0; tt < 2; ++tt) {
        const u32 wt = tt ? wt1 : wt0;
#pragma unroll
        for (int r = 0; r < 16; ++r) {
          const int bit = (r & 3) + 8 * (r >> 2);
          const float p = exp2f((float)st[tt][r]);
          st[tt][r] = ((wt >> bit) & 1u) ? p : 0.f;
        }
      }

      // ---- pb = straight pack of st under k-map 4hi+(j<4?j:j+4) ----
      u32x4 pb[4];
#pragma unroll
      for (int ks = 0; ks < 4; ++ks) {
        const int tt = ks >> 1, e = ks & 1;
#pragma unroll
        for (int w2 = 0; w2 < 4; ++w2)
          pb[ks][w2] = pk2((float)st[tt][8 * e + 2 * w2], (float)st[tt][8 * e + 2 * w2 + 1]);
      }

      // ---- l += colsum via ones-MFMA; PV with 2x b64 V-frags (same k-map) ----
      __builtin_amdgcn_s_setprio(1);
#pragma unroll
      for (int ks = 0; ks < 4; ++ks)
        lacc = MFMA32(ones8, __builtin_bit_cast(bf16x8, pb[ks]), lacc);
#pragma unroll
      for (int dt = 0; dt < 2; ++dt) {
        const int row = 32 * dt + ql;
        const bf16* vbase = &Vs[buf][row * 128];
#pragma unroll
        for (int ks = 0; ks < 4; ++ks) {
          const int slot0 = (8 * hh + 2 * ks) ^ (row & 7);
          bf16x4 vlo = *(const bf16x4*)&vbase[slot0 * 8 + 4 * hi];
          bf16x4 vhi = *(const bf16x4*)&vbase[(slot0 ^ 1) * 8 + 4 * hi];
          bf16x8 vf;
#pragma unroll
          for (int j = 0; j < 4; ++j) { vf[j] = vlo[j]; vf[4 + j] = vhi[j]; }
          oacc[dt] = MFMA32(vf, __builtin_bit_cast(bf16x8, pb[ks]), oacc[dt]);
        }
      }
      __builtin_amdgcn_s_setprio(0);
    }

    // stage + mask ops were issued a full 128-k compute ago -> retire instantly
    asm volatile("s_waitcnt vmcnt(0)" ::: "memory");
    __builtin_amdgcn_s_barrier();
    __builtin_amdgcn_sched_barrier(0);
    w0 = w0n; w1 = w1n;
  }

  const float lsum = lacc[0];  // every reg row holds the same column-sum
  if constexpr (SPLITS == 2) {
    float* opr = opart + ((size_t)(half * 32 + bh) * Sc + qrow) * 64;
#pragma unroll
    for (int dt = 0; dt < 2; ++dt)
#pragma unroll
      for (int i = 0; i < 4; ++i) {
        f32x4 o4;
#pragma unroll
        for (int rr = 0; rr < 4; ++rr) o4[rr] = oacc[dt][4 * i + rr];
        *(f32x4*)&opr[32 * dt + 8 * i + 4 * hi] = o4;
      }
    if (hi == 0) {
      float2 v2; v2.x = 0.f; v2.y = lsum;  // fixed base: m = 0 for both halves
      ml[(size_t)(half * 32 + bh) * Sc + qrow] = v2;
    }
  } else {
    const float rinv = 1.f / fmaxf(lsum, 1e-35f);
    bf16* cp = ctx + (size_t)(b * Sc + qrow) * Dc + h * DKc;
#pragma unroll
    for (int dt = 0; dt < 2; ++dt)
#pragma unroll
      for (int i = 0; i < 4; ++i) {
        bf16x4 o4;
#pragma unroll
        for (int rr = 0; rr < 4; ++rr) o4[rr] = (bf16)(oacc[dt][4 * i + rr] * rinv);
        *(bf16x4*)&cp[32 * dt + 8 * i + 4 * hi] = o4;
      }
  }
}

// ---------------- combine the two KV-splits: exact f32 flash merge ----------------
__global__ __launch_bounds__(256) void combine_kernel(const float* __restrict__ op,
                                                      const float2* __restrict__ ml,
                                                      bf16* __restrict__ ctx) {
  const int wv = threadIdx.x >> 6, lane = threadIdx.x & 63;
  const size_t row = (size_t)blockIdx.x * 4 + wv;      // bh*2048 + q, 0..65535
  const int bh = (int)(row >> 11), q = (int)(row & 2047);
  const int b = bh >> 4, h = bh & 15;
  const float2 ml0 = ml[row], ml1 = ml[65536 + row];
  const float o0 = op[row * 64 + lane];
  const float o1 = op[(size_t)65536 * 64 + row * 64 + lane];
  const float m = fmaxf(ml0.x, ml1.x);
  const float a0 = exp2f(ml0.x - m), a1 = exp2f(ml1.x - m);
  const float l = fmaxf(a0 * ml0.y + a1 * ml1.y, 1e-35f);
  const float o = (a0 * o0 + a1 * o1) / l;
  ctx[((size_t)(b * Sc + q)) * Dc + h * DKc + lane] = (bf16)o;
}

extern "C" void kernel_launch(void* const* d_in, const int* in_sizes, int n_in,
                              void* d_out, int out_size, void* d_ws, size_t ws_size,
                              hipStream_t stream) {
  (void)in_sizes; (void)n_in; (void)out_size;
  const float* q  = (const float*)d_in[0];
  const float* k  = (const float*)d_in[1];
  const float* v  = (const float*)d_in[2];
  const float* Wq = (const float*)d_in[3];
  const float* bq = (const float*)d_in[4];
  const float* Wk = (const float*)d_in[5];
  const float* bk = (const float*)d_in[6];
  const float* Wv = (const float*)d_in[7];
  const float* bv = (const float*)d_in[8];
  const float* Wo = (const float*)d_in[9];
  const float* bo = (const float*)d_in[10];
  const int* mask = (const int*)d_in[11];

  char* ws = (char*)d_ws;
  size_t off = 0;
  auto take = [&](size_t bytes) -> void* {
    void* p = ws + off;
    off += (bytes + 255) & ~(size_t)255;
    return p;
  };
  bf16* qh  = (bf16*)take((size_t)Mc * Dc * 2);
  bf16* kh  = (bf16*)take((size_t)Mc * Dc * 2);
  bf16* vt  = (bf16*)take((size_t)Mc * Dc * 2);
  bf16* ctx = (bf16*)take((size_t)Mc * Dc * 2);
  u64* mbits = (u64*)take((size_t)Bc * Sc * MW * 8);   // transposed: [b][kw][q]
  bf16* wqb = (bf16*)take((size_t)Dc * Dc * 2);
  bf16* wkb = (bf16*)take((size_t)Dc * Dc * 2);
  bf16* wvb = (bf16*)take((size_t)Dc * Dc * 2);
  bf16* wob = (bf16*)take((size_t)Dc * Dc * 2);
  float* opart = (float*)take((size_t)2 * 32 * Sc * 64 * 4);   // [split][bh][q][64] f32
  float2* mlb = (float2*)take((size_t)2 * 32 * Sc * 8);        // [split][bh][q] (m,l)
  const bool split2 = off <= ws_size;

  convw_kernel<<<dim3(512, 4), 256, 0, stream>>>(Wq, Wk, Wv, Wo, wqb, wkb, wvb, wob);
  packmask_kernel<<<512, 256, 0, stream>>>(mask, mbits, Bc * Sc * Sc / 64);
  gemm_qkv_kernel<<<768, 256, 0, stream>>>(q, k, v, wqb, wkb, wvb, bq, bk, bv, qh, kh, vt);
  if (split2) {
    attn_kernel<2><<<1024, 256, 0, stream>>>(qh, kh, vt, mbits, ctx, opart, mlb);
    combine_kernel<<<16384, 256, 0, stream>>>(opart, mlb, ctx);
  } else {
    attn_kernel<1><<<512, 256, 0, stream>>>(qh, kh, vt, mbits, ctx, opart, mlb);
  }
  gemm_o_kernel<<<512, 256, 0, stream>>>(ctx, wob, bo, (float*)d_out);
}

// Round 8
// 169.998 us; speedup vs baseline: 1.0701x; 1.0449x over previous
//
#include <hip/hip_runtime.h>
#include <hip/hip_bf16.h>
#include <stdint.h>

typedef __bf16 bf16;
typedef __bf16 bf16x2 __attribute__((ext_vector_type(2)));
typedef __bf16 bf16x4 __attribute__((ext_vector_type(4)));
typedef __bf16 bf16x8 __attribute__((ext_vector_type(8)));
typedef float f32x4 __attribute__((ext_vector_type(4)));
typedef float f32x16 __attribute__((ext_vector_type(16)));
typedef unsigned int u32;
typedef u32 u32x4 __attribute__((ext_vector_type(4)));
typedef unsigned long long u64;

#define MFMA16(a, b, c) __builtin_amdgcn_mfma_f32_16x16x32_bf16((a), (b), (c), 0, 0, 0)
#define MFMA32(a, b, c) __builtin_amdgcn_mfma_f32_32x32x16_bf16((a), (b), (c), 0, 0, 0)

constexpr int Bc = 2, Sc = 2048, Dc = 1024, Hc = 16, DKc = 64;
constexpr int Mc = Bc * Sc;
constexpr int MW = Sc / 64;
// 1/sqrt(dk) * log2(e): scores produced directly in log2 domain
#define QSCALE 0.1803368801111731f

__device__ __forceinline__ u32 pk2(float a, float b) {
  bf16x2 t; t[0] = (bf16)a; t[1] = (bf16)b;
  return __builtin_bit_cast(u32, t);
}

__device__ __forceinline__ void gl_lds16(const void* g, void* l) {
  __builtin_amdgcn_global_load_lds((const __attribute__((address_space(1))) void*)g,
                                   (__attribute__((address_space(3))) void*)l, 16, 0, 0);
}

// ---------------- weights fp32 -> bf16 (Wq also scaled by QSCALE) ----------------
__global__ __launch_bounds__(256) void convw_kernel(
    const float* __restrict__ wq, const float* __restrict__ wk,
    const float* __restrict__ wv, const float* __restrict__ wo,
    bf16* __restrict__ dq, bf16* __restrict__ dk2, bf16* __restrict__ dv, bf16* __restrict__ dwo) {
  const int a = blockIdx.y;
  const float* src = a == 0 ? wq : a == 1 ? wk : a == 2 ? wv : wo;
  bf16* dst = a == 0 ? dq : a == 1 ? dk2 : a == 2 ? dv : dwo;
  const float sc = a == 0 ? QSCALE : 1.0f;
  const size_t i = ((size_t)blockIdx.x * 256 + threadIdx.x) * 8;
  f32x4 x0 = *(const f32x4*)&src[i];
  f32x4 x1 = *(const f32x4*)&src[i + 4];
  bf16x8 o;
#pragma unroll
  for (int j = 0; j < 4; ++j) { o[j] = (bf16)(x0[j] * sc); o[4 + j] = (bf16)(x1[j] * sc); }
  *(bf16x8*)&dst[i] = o;
}

// ---------------- mask (int32 0/1) -> transposed bitmask mbT[b][kw][q] ----------------
__global__ __launch_bounds__(256) void packmask_kernel(const int* __restrict__ mask,
                                                       u64* __restrict__ mbT, int nwords) {
  const int lane = threadIdx.x & 63;
  const int wid = (blockIdx.x * blockDim.x + threadIdx.x) >> 6;
  const int nw = (gridDim.x * blockDim.x) >> 6;
  for (int i = wid; i < nwords; i += nw) {
    int v = mask[(size_t)i * 64 + lane];
    u64 bits = __ballot(v != 0);
    if (lane == 0) {
      const int kw = i & (MW - 1), bq = i >> 5;
      const int b = bq >> 11, q = bq & (Sc - 1);
      mbT[((size_t)(b * MW + kw)) * Sc + q] = bits;
    }
  }
}

// ---------------- fused QKV GEMM (V store now k-permuted: swap bits 2<->3 of s) ----------------
__global__ __launch_bounds__(256, 2) void gemm_qkv_kernel(
    const float* __restrict__ q, const float* __restrict__ k, const float* __restrict__ v,
    const bf16* __restrict__ wq, const bf16* __restrict__ wk, const bf16* __restrict__ wv,
    const float* __restrict__ bq, const float* __restrict__ bk, const float* __restrict__ bv,
    bf16* __restrict__ qh, bf16* __restrict__ kh, bf16* __restrict__ vt) {
  __shared__ float As[128 * 64];
  __shared__ bf16 Bs[128 * 64];
  const int d = blockIdx.x;
  const int xcd = d & 7, idx = d >> 3;
  const int proj = idx >> 5, w = idx & 31;
  const int n0 = (w & 7) * 128;
  const int m0 = (xcd * 4 + (w >> 3)) * 128;
  const float* Af = proj == 0 ? q : proj == 1 ? k : v;
  const bf16* Bw = proj == 0 ? wq : proj == 1 ? wk : wv;
  const float* bias = proj == 0 ? bq : proj == 1 ? bk : bv;

  const int t = threadIdx.x, lane = t & 63, wv4 = t >> 6;
  const int c = lane & 15, g = lane >> 4;
  const int wr = wv4 >> 1, wc = wv4 & 1;

  f32x4 acc[4][4];
#pragma unroll
  for (int i = 0; i < 4; ++i)
#pragma unroll
    for (int j = 0; j < 4; ++j) acc[i][j] = (f32x4){0.f, 0.f, 0.f, 0.f};

  const int arow_l = lane >> 4;
  const int aslot_l = lane & 15;
  const int brow_l = lane >> 3;
  const int bslot_l = (lane & 7) ^ brow_l;

  for (int k0 = 0; k0 < Dc; k0 += 64) {
#pragma unroll
    for (int u = 0; u < 8; ++u) {
      const int ch = wv4 * 8 + u;
      const int row = ch * 4 + arow_l;
      const int slot = aslot_l ^ (row & 7);
      gl_lds16(&Af[(size_t)(m0 + row) * Dc + k0 + slot * 4], &As[ch * 256]);
    }
#pragma unroll
    for (int u = 0; u < 4; ++u) {
      const int ch = wv4 * 4 + u;
      const int row = ch * 8 + brow_l;
      gl_lds16(&Bw[(size_t)(n0 + row) * Dc + k0 + bslot_l * 8], &Bs[ch * 512]);
    }
    __syncthreads();
#pragma unroll
    for (int ks = 0; ks < 2; ++ks) {
      bf16x8 af[4], bfr[4];
#pragma unroll
      for (int mt = 0; mt < 4; ++mt) {
        const int row = wr * 64 + mt * 16 + c;
        const int s0 = (8 * ks + 2 * g) ^ (c & 7);
        const int s1 = (8 * ks + 2 * g + 1) ^ (c & 7);
        f32x4 lo = *(const f32x4*)&As[row * 64 + s0 * 4];
        f32x4 hi2 = *(const f32x4*)&As[row * 64 + s1 * 4];
#pragma unroll
        for (int j = 0; j < 4; ++j) { af[mt][j] = (bf16)lo[j]; af[mt][4 + j] = (bf16)hi2[j]; }
      }
#pragma unroll
      for (int nt = 0; nt < 4; ++nt) {
        const int row = wc * 64 + nt * 16 + c;
        const int sl = (4 * ks + g) ^ (c & 7);
        bfr[nt] = *(const bf16x8*)&Bs[row * 64 + sl * 8];
      }
#pragma unroll
      for (int mt = 0; mt < 4; ++mt)
#pragma unroll
        for (int nt = 0; nt < 4; ++nt) acc[mt][nt] = MFMA16(af[mt], bfr[nt], acc[mt][nt]);
    }
    __syncthreads();
  }

  const float bsc = proj == 0 ? QSCALE : 1.0f;
  const int colb = n0 + wc * 64 + c;
  const int mrowb = m0 + wr * 64 + 4 * g;
#pragma unroll
  for (int mt = 0; mt < 4; ++mt) {
#pragma unroll
    for (int nt = 0; nt < 4; ++nt) {
      const int col = colb + nt * 16;
      const int mrow = mrowb + mt * 16;
      const float bb = bias[col] * bsc;
      f32x4 a = acc[mt][nt];
      if (proj == 0) {
#pragma unroll
        for (int r = 0; r < 4; ++r) qh[(size_t)(mrow + r) * Dc + col] = (bf16)(a[r] + bb);
      } else if (proj == 1) {
        const int hh = col >> 6, dd = col & 63;
#pragma unroll
        for (int r = 0; r < 4; ++r) {
          const int mr = mrow + r;
          kh[((size_t)((mr >> 11) * Hc + hh) * Sc + (mr & (Sc - 1))) * DKc + dd] = (bf16)(a[r] + bb);
        }
      } else {
        // V: transposed [B][H][64][S] with s bits 2<->3 swapped (PV b128 fragment layout)
        const int batch = mrow >> 11, s = mrow & (Sc - 1);
        const int s2 = (s & ~15) | ((s & 4) << 1) | ((s & 8) >> 1);  // low 2 bits are r
        const int hh = col >> 6, dd = col & 63;
        bf16x4 pkv;
#pragma unroll
        for (int r = 0; r < 4; ++r) pkv[r] = (bf16)(a[r] + bb);
        *(bf16x4*)&vt[((size_t)((batch * Hc + hh) * DKc + dd)) * Sc + s2] = pkv;
      }
    }
  }
}

// ---------------- output GEMM (unchanged) ----------------
__global__ __launch_bounds__(256, 2) void gemm_o_kernel(const bf16* __restrict__ ctxp,
                                                        const bf16* __restrict__ wo,
                                                        const float* __restrict__ bo,
                                                        float* __restrict__ outp) {
  __shared__ bf16 As[128 * 64];
  __shared__ bf16 Bs[64 * 64];
  const int d = blockIdx.x;
  const int xcd = d & 7, idx = d >> 3;
  const int n0 = (idx & 15) * 64;
  const int m0 = (xcd * 4 + (idx >> 4)) * 128;

  const int t = threadIdx.x, lane = t & 63, wv4 = t >> 6;
  const int c = lane & 15, g = lane >> 4;
  const int brow_l = lane >> 3;
  const int bslot_l = (lane & 7) ^ brow_l;

  f32x4 acc[2][4];
#pragma unroll
  for (int i = 0; i < 2; ++i)
#pragma unroll
    for (int j = 0; j < 4; ++j) acc[i][j] = (f32x4){0.f, 0.f, 0.f, 0.f};

  for (int k0 = 0; k0 < Dc; k0 += 64) {
#pragma unroll
    for (int u = 0; u < 4; ++u) {
      const int ch = wv4 * 4 + u;
      const int row = ch * 8 + brow_l;
      gl_lds16(&ctxp[(size_t)(m0 + row) * Dc + k0 + bslot_l * 8], &As[ch * 512]);
    }
    {
      const int ch = wv4;
      const int row = ch * 8 + brow_l;
      gl_lds16(&wo[(size_t)(n0 + row) * Dc + k0 + bslot_l * 8], &Bs[ch * 512]);
      const int ch2 = 4 + wv4;
      const int row2 = ch2 * 8 + brow_l;
      gl_lds16(&wo[(size_t)(n0 + row2) * Dc + k0 + bslot_l * 8], &Bs[ch2 * 512]);
    }
    __syncthreads();
#pragma unroll
    for (int ks = 0; ks < 2; ++ks) {
      bf16x8 af[2], bfr[4];
#pragma unroll
      for (int mt = 0; mt < 2; ++mt) {
        const int row = wv4 * 32 + mt * 16 + c;
        const int sl = (4 * ks + g) ^ (c & 7);
        af[mt] = *(const bf16x8*)&As[row * 64 + sl * 8];
      }
#pragma unroll
      for (int nt = 0; nt < 4; ++nt) {
        const int row = nt * 16 + c;
        const int sl = (4 * ks + g) ^ (c & 7);
        bfr[nt] = *(const bf16x8*)&Bs[row * 64 + sl * 8];
      }
#pragma unroll
      for (int mt = 0; mt < 2; ++mt)
#pragma unroll
        for (int nt = 0; nt < 4; ++nt) acc[mt][nt] = MFMA16(af[mt], bfr[nt], acc[mt][nt]);
    }
    __syncthreads();
  }

  const int colb = n0 + c;
  const int mrowb = m0 + wv4 * 32 + 4 * g;
#pragma unroll
  for (int mt = 0; mt < 2; ++mt)
#pragma unroll
    for (int nt = 0; nt < 4; ++nt) {
      const int col = colb + nt * 16;
      const int mrow = mrowb + mt * 16;
      const float bb = bo[col];
      f32x4 a = acc[mt][nt];
#pragma unroll
      for (int r = 0; r < 4; ++r) outp[(size_t)(mrow + r) * Dc + col] = a[r] + bb;
    }
}

// ---------------- flash attention: KVBLK=64, 32KB LDS, 4 blocks/CU, b128 PV ----------------
// k-map (both PV operands): k = base + 4hi + (j<4?j:j+4). st regs natively match (QK C-layout);
// V matches because vt has s-bits 2<->3 swapped, so 16B of Vs = one (ks,hi) 8-group.
template <int SPLITS>
__global__ __launch_bounds__(256, 4) void attn_kernel(const bf16* __restrict__ qh,
                                                      const bf16* __restrict__ kh,
                                                      const bf16* __restrict__ vt,
                                                      const u64* __restrict__ mbT,
                                                      bf16* __restrict__ ctx,
                                                      float* __restrict__ opart,
                                                      float2* __restrict__ ml) {
  __shared__ bf16 Ks[2][64 * 64];   // [buf][k-row 64][64], 16B slots XOR-swizzled by row&7
  __shared__ bf16 Vs[2][64 * 64];   // [buf][d-row 64][64 perm k], same swizzle
  const int d = blockIdx.x;
  const int xcd = d & 7, idx = d >> 3;
  int bh, qt, half;
  if constexpr (SPLITS == 2) {
    bh = xcd * 4 + (idx >> 5);
    const int sub = idx & 31;
    qt = sub >> 1; half = sub & 1;
  } else {
    bh = xcd * 4 + (idx >> 4);
    qt = idx & 15; half = 0;
  }
  const int b = bh >> 4, h = bh & 15;
  const int lane = threadIdx.x & 63, wv4 = threadIdx.x >> 6;
  const int ql = lane & 31, hi = lane >> 5;
  const int qrow = qt * 128 + wv4 * 32 + ql;

  const bf16* Qp = qh + (size_t)(b * Sc + qrow) * Dc + h * DKc;
  const bf16* Kp = kh + (size_t)(b * Hc + h) * Sc * DKc;
  const bf16* Vp = vt + (size_t)(b * Hc + h) * DKc * Sc;
  const u64* mbp = mbT + (size_t)b * MW * Sc;  // [kw][q], q-coalesced

  const int k0 = half * (Sc / SPLITS);
  constexpr int NIT = (Sc / SPLITS) / 64;

  const int srow = lane >> 3, sslot = lane & 7;  // staging: 8 rows x 8 slots(16B) per 1KB chunk
  auto stage = [&](int buf, int kt) {
#pragma unroll
    for (int u = 0; u < 2; ++u) {
      const int ch = wv4 * 2 + u;
      const int r = ch * 8 + srow;
      gl_lds16(&Kp[(size_t)(kt + r) * DKc + (size_t)((sslot ^ (r & 7)) * 8)], &Ks[buf][ch * 512]);
    }
#pragma unroll
    for (int u = 0; u < 2; ++u) {
      const int ch = wv4 * 2 + u;
      const int r = ch * 8 + srow;
      gl_lds16(&Vp[(size_t)r * Sc + kt + (size_t)((sslot ^ (r & 7)) * 8)], &Vs[buf][ch * 512]);
    }
  };

  bf16x8 qf[4];
#pragma unroll
  for (int ka = 0; ka < 4; ++ka) qf[ka] = *(const bf16x8*)&Qp[16 * ka + 8 * hi];

  bf16x8 ones8;
#pragma unroll
  for (int j = 0; j < 8; ++j) ones8[j] = (bf16)1.0f;

  f32x16 oacc[2], lacc;
#pragma unroll
  for (int i = 0; i < 2; ++i)
#pragma unroll
    for (int r = 0; r < 16; ++r) oacc[i][r] = 0.f;
#pragma unroll
  for (int r = 0; r < 16; ++r) lacc[r] = 0.f;

  // prologue: stage tile 0 + its mask word (coalesced), drain, barrier
  stage(0, k0);
  u64 w = mbp[(size_t)(k0 >> 6) * Sc + qrow];
  asm volatile("s_waitcnt vmcnt(0)" ::: "memory");
  __builtin_amdgcn_s_barrier();
  __builtin_amdgcn_sched_barrier(0);

  for (int it = 0; it < NIT; ++it) {
    const int kt = k0 + it * 64;
    const int buf = it & 1;
    const int ktn = (it + 1 < NIT) ? kt + 64 : kt;  // clamp: harmless restage on last iter
    stage(buf ^ 1, ktn);
    const u64 wn = mbp[(size_t)(ktn >> 6) * Sc + qrow];

    // ---- QK^T from LDS: st[tt] covers k in [kt+32tt, +32), all 32 q ----
    f32x16 st[2];
#pragma unroll
    for (int tt = 0; tt < 2; ++tt) {
      const int row = 32 * tt + ql;
      const bf16* kbase = &Ks[buf][row * 64];
      f32x16 z;
#pragma unroll
      for (int r = 0; r < 16; ++r) z[r] = 0.f;
      __builtin_amdgcn_s_setprio(1);
#pragma unroll
      for (int ka = 0; ka < 4; ++ka) {
        bf16x8 kf = *(const bf16x8*)&kbase[((2 * ka + hi) ^ (row & 7)) * 8];
        z = MFMA32(kf, qf[ka], z);
      }
      __builtin_amdgcn_s_setprio(0);
      st[tt] = z;
    }

    // ---- fixed-base softmax: p = exp2(s) raw (scale cancels in o = sum(p*v)/sum(p)) ----
    const u32 wt0 = (u32)(w >> (4 * hi));
    const u32 wt1 = (u32)(w >> (32 + 4 * hi));
#pragma unroll
    for (int tt = 0; tt < 2; ++tt) {
      const u32 wt = tt ? wt1 : wt0;
#pragma unroll
      for (int r = 0; r < 16; ++r) {
        const int bit = (r & 3) + 8 * (r >> 2);
        const float p = __builtin_amdgcn_exp2f((float)st[tt][r]);
        st[tt][r] = ((wt >> bit) & 1u) ? p : 0.f;
      }
    }

    // ---- pb = straight pack of st under the shared k-map ----
    u32x4 pb[4];
#pragma unroll
    for (int ks = 0; ks < 4; ++ks) {
      const int tt = ks >> 1, e = ks & 1;
#pragma unroll
      for (int w2 = 0; w2 < 4; ++w2)
        pb[ks][w2] = pk2((float)st[tt][8 * e + 2 * w2], (float)st[tt][8 * e + 2 * w2 + 1]);
    }

    // ---- l += colsum via ones-MFMA; PV with single-b128 V-frags ----
    __builtin_amdgcn_s_setprio(1);
#pragma unroll
    for (int ks = 0; ks < 4; ++ks)
      lacc = MFMA32(ones8, __builtin_bit_cast(bf16x8, pb[ks]), lacc);
#pragma unroll
    for (int dt = 0; dt < 2; ++dt) {
      const int row = 32 * dt + ql;
      const bf16* vbase = &Vs[buf][row * 64];
#pragma unroll
      for (int ks = 0; ks < 4; ++ks) {
        bf16x8 vf = *(const bf16x8*)&vbase[((2 * ks + hi) ^ (row & 7)) * 8];
        oacc[dt] = MFMA32(vf, __builtin_bit_cast(bf16x8, pb[ks]), oacc[dt]);
      }
    }
    __builtin_amdgcn_s_setprio(0);

    // stage + mask ops were issued a full compute ago -> retire instantly
    asm volatile("s_waitcnt vmcnt(0)" ::: "memory");
    __builtin_amdgcn_s_barrier();
    __builtin_amdgcn_sched_barrier(0);
    w = wn;
  }

  const float lsum = lacc[0];  // every reg row holds the same column-sum
  if constexpr (SPLITS == 2) {
    float* opr = opart + ((size_t)(half * 32 + bh) * Sc + qrow) * 64;
#pragma unroll
    for (int dt = 0; dt < 2; ++dt)
#pragma unroll
      for (int i = 0; i < 4; ++i) {
        f32x4 o4;
#pragma unroll
        for (int rr = 0; rr < 4; ++rr) o4[rr] = oacc[dt][4 * i + rr];
        *(f32x4*)&opr[32 * dt + 8 * i + 4 * hi] = o4;
      }
    if (hi == 0) {
      float2 v2; v2.x = 0.f; v2.y = lsum;  // fixed base: m = 0 for both halves
      ml[(size_t)(half * 32 + bh) * Sc + qrow] = v2;
    }
  } else {
    const float rinv = 1.f / fmaxf(lsum, 1e-35f);
    bf16* cp = ctx + (size_t)(b * Sc + qrow) * Dc + h * DKc;
#pragma unroll
    for (int dt = 0; dt < 2; ++dt)
#pragma unroll
      for (int i = 0; i < 4; ++i) {
        bf16x4 o4;
#pragma unroll
        for (int rr = 0; rr < 4; ++rr) o4[rr] = (bf16)(oacc[dt][4 * i + rr] * rinv);
        *(bf16x4*)&cp[32 * dt + 8 * i + 4 * hi] = o4;
      }
  }
}

// ---------------- combine the two KV-splits: exact f32 flash merge ----------------
__global__ __launch_bounds__(256) void combine_kernel(const float* __restrict__ op,
                                                      const float2* __restrict__ ml,
                                                      bf16* __restrict__ ctx) {
  const int wv = threadIdx.x >> 6, lane = threadIdx.x & 63;
  const size_t row = (size_t)blockIdx.x * 4 + wv;      // bh*2048 + q, 0..65535
  const int bh = (int)(row >> 11), q = (int)(row & 2047);
  const int b = bh >> 4, h = bh & 15;
  const float2 ml0 = ml[row], ml1 = ml[65536 + row];
  const float o0 = op[row * 64 + lane];
  const float o1 = op[(size_t)65536 * 64 + row * 64 + lane];
  const float m = fmaxf(ml0.x, ml1.x);
  const float a0 = exp2f(ml0.x - m), a1 = exp2f(ml1.x - m);
  const float l = fmaxf(a0 * ml0.y + a1 * ml1.y, 1e-35f);
  const float o = (a0 * o0 + a1 * o1) / l;
  ctx[((size_t)(b * Sc + q)) * Dc + h * DKc + lane] = (bf16)o;
}

extern "C" void kernel_launch(void* const* d_in, const int* in_sizes, int n_in,
                              void* d_out, int out_size, void* d_ws, size_t ws_size,
                              hipStream_t stream) {
  (void)in_sizes; (void)n_in; (void)out_size;
  const float* q  = (const float*)d_in[0];
  const float* k  = (const float*)d_in[1];
  const float* v  = (const float*)d_in[2];
  const float* Wq = (const float*)d_in[3];
  const float* bq = (const float*)d_in[4];
  const float* Wk = (const float*)d_in[5];
  const float* bk = (const float*)d_in[6];
  const float* Wv = (const float*)d_in[7];
  const float* bv = (const float*)d_in[8];
  const float* Wo = (const float*)d_in[9];
  const float* bo = (const float*)d_in[10];
  const int* mask = (const int*)d_in[11];

  char* ws = (char*)d_ws;
  size_t off = 0;
  auto take = [&](size_t bytes) -> void* {
    void* p = ws + off;
    off += (bytes + 255) & ~(size_t)255;
    return p;
  };
  bf16* qh  = (bf16*)take((size_t)Mc * Dc * 2);
  bf16* kh  = (bf16*)take((size_t)Mc * Dc * 2);
  bf16* vt  = (bf16*)take((size_t)Mc * Dc * 2);
  bf16* ctx = (bf16*)take((size_t)Mc * Dc * 2);
  u64* mbits = (u64*)take((size_t)Bc * Sc * MW * 8);   // transposed: [b][kw][q]
  bf16* wqb = (bf16*)take((size_t)Dc * Dc * 2);
  bf16* wkb = (bf16*)take((size_t)Dc * Dc * 2);
  bf16* wvb = (bf16*)take((size_t)Dc * Dc * 2);
  bf16* wob = (bf16*)take((size_t)Dc * Dc * 2);
  float* opart = (float*)take((size_t)2 * 32 * Sc * 64 * 4);   // [split][bh][q][64] f32
  float2* mlb = (float2*)take((size_t)2 * 32 * Sc * 8);        // [split][bh][q] (m,l)
  const bool split2 = off <= ws_size;

  convw_kernel<<<dim3(512, 4), 256, 0, stream>>>(Wq, Wk, Wv, Wo, wqb, wkb, wvb, wob);
  packmask_kernel<<<512, 256, 0, stream>>>(mask, mbits, Bc * Sc * Sc / 64);
  gemm_qkv_kernel<<<768, 256, 0, stream>>>(q, k, v, wqb, wkb, wvb, bq, bk, bv, qh, kh, vt);
  if (split2) {
    attn_kernel<2><<<1024, 256, 0, stream>>>(qh, kh, vt, mbits, ctx, opart, mlb);
    combine_kernel<<<16384, 256, 0, stream>>>(opart, mlb, ctx);
  } else {
    attn_kernel<1><<<512, 256, 0, stream>>>(qh, kh, vt, mbits, ctx, opart, mlb);
  }
  gemm_o_kernel<<<512, 256, 0, stream>>>(ctx, wob, bo, (float*)d_out);
}